// Round 2
// baseline (441.561 us; speedup 1.0000x reference)
//
#include <hip/hip_runtime.h>

#define G_TOT 2016
#define NGB32 63
#define HSTR 36   // hbuf row stride (f16): 72B, b64-aligned, bank-conflict-free
#define CSTR 33   // cob row stride (f32)

typedef _Float16 f16;
typedef __attribute__((ext_vector_type(4))) _Float16 v4h;
typedef __attribute__((ext_vector_type(8))) _Float16 v8h;
typedef __attribute__((ext_vector_type(4))) float v4f;

// ---------------------------------------------------------------------------
// Prep: gather Y into x32-MFMA-fragment-ordered f16 tables (per 32-g block).
// x32 fragment layout = two stacked x16 halves: elems 0-3 <-> k in [0,16),
// elems 4-7 <-> k in [16,32).
// A1buf: A-operand of G^T gemm (m=g, k=ksh). B2buf: B-operand of CO gemm
// (k=g, n=ksh), qw folded in.
// ---------------------------------------------------------------------------
__global__ void vg_prep(const float* __restrict__ Y, const float* __restrict__ qw,
                        f16* __restrict__ A1buf, f16* __restrict__ B2buf) {
    const int gb = blockIdx.x;
    const int lane = threadIdx.x & 63;
    const int lhi = lane >> 4, llo = lane & 15;
#pragma unroll
    for (int gh = 0; gh < 2; ++gh) {
        const int g = gb * 32 + gh * 16 + llo;
#pragma unroll
        for (int j = 0; j < 8; ++j) {
            const int k = (j < 4) ? (lhi * 4 + j) : (16 + lhi * 4 + (j - 4));
            const float v = (k < 25) ? Y[k * G_TOT + g] : 0.0f;
            A1buf[((gb * 2 + gh) * 64 + lane) * 8 + j] = (f16)v;
        }
    }
#pragma unroll
    for (int t = 0; t < 2; ++t) {
        const int k = t * 16 + llo;
#pragma unroll
        for (int j = 0; j < 8; ++j) {
            const int g = gb * 32 + ((j < 4) ? (lhi * 4 + j) : (16 + lhi * 4 + (j - 4)));
            const float v = (k < 25) ? Y[k * G_TOT + g] * qw[g] : 0.0f;
            B2buf[((gb * 2 + t) * 64 + lane) * 8 + j] = (f16)v;
        }
    }
}

// ---------------------------------------------------------------------------
// Main fused kernel: one block per (n, parity), 4 waves, 32-g blocks.
// MFMA1 (swapped, x32): D1[g][row] = sum_ksh Y[ksh][g] * h[row][ksh]
// cross in-register -> lands exactly in A-fragment of MFMA2 (k=g)
// MFMA2 (x32): CO[row][ksh] += sum_g cr[row][g] * Yw[ksh][g]
// ---------------------------------------------------------------------------
template <bool USE_WS>
__global__ __launch_bounds__(256, 4)
void vg_main(const float* __restrict__ x1, const float* __restrict__ x2,
             const float* __restrict__ W1s, const float* __restrict__ W2s,
             const float* __restrict__ Wouts, const float* __restrict__ Y,
             const float* __restrict__ qw,
             const f16* __restrict__ A1buf, const f16* __restrict__ B2buf,
             float* __restrict__ out) {
    __shared__ __align__(16) char smem[26496];
    f16* hbuf = (f16*)smem;                 // [2][96][HSTR] f16
    float* cob = (float*)(smem + 13824);    // [96][CSTR] f32

    const int bid = blockIdx.x;
    const int n = bid / 3, p = bid % 3;
    const int tid = threadIdx.x;
    const int wid = tid >> 6;
    const int lane = tid & 63;
    const int lhi = lane >> 4, llo = lane & 15;

    // ---- phase 0a: zero hbuf (padding cols must be 0)
    for (int i = tid; i < 3456; i += 256) ((float*)smem)[i] = 0.0f;
    __syncthreads();

    // ---- phase 0b: h[row=v*32+c][k] = sum_f x[f,v,k] * W[l_k,f,c], cast f16.
    // x reads are uniform per 32-lane group (broadcast); W reads coalesced in c.
    {
        const int c = tid & 31, grp = tid >> 5;
        const float* x1n = x1 + n * 2400;
        const float* x2n = x2 + n * 2400;
        const float* W1p = W1s + p * 5120;
        const float* W2p = W2s + p * 5120;
        for (int vk = grp; vk < 75; vk += 8) {
            const int v = vk / 25, k = vk - v * 25;
            const int l = (k >= 16) ? 4 : (k >= 9) ? 3 : (k >= 4) ? 2 : (k >= 1) ? 1 : 0;
            const float* w1 = W1p + l * 1024 + c;
            const float* w2 = W2p + l * 1024 + c;
            float a1 = 0.0f, a2s = 0.0f;
#pragma unroll
            for (int f = 0; f < 32; ++f) {
                a1 += x1n[f * 75 + vk] * w1[f * 32];
                a2s += x2n[f * 75 + vk] * w2[f * 32];
            }
            const int row = v * 32 + c;
            hbuf[row * HSTR + k] = (f16)a1;
            hbuf[96 * HSTR + row * HSTR + k] = (f16)a2s;
        }
    }
    __syncthreads();

    // ---- hoisted h fragments (B-operand of MFMA1, x32): elems 0-3 k<16, 4-7 k>=16
    v8h hfrag[2][6];
#pragma unroll
    for (int s = 0; s < 2; ++s)
#pragma unroll
        for (int Rn = 0; Rn < 6; ++Rn) {
            const f16* base = &hbuf[s * 96 * HSTR + (Rn * 16 + llo) * HSTR + lhi * 4];
            v4h lo = *(const v4h*)base;
            v4h hi = *(const v4h*)(base + 16);
            hfrag[s][Rn] = __builtin_shufflevector(lo, hi, 0, 1, 2, 3, 4, 5, 6, 7);
        }

    const v4f zero4 = {0.0f, 0.0f, 0.0f, 0.0f};
    v4f coacc[6][2];
#pragma unroll
    for (int Rn = 0; Rn < 6; ++Rn)
#pragma unroll
        for (int t = 0; t < 2; ++t) coacc[Rn][t] = zero4;

    // ---- main loop over 32-g blocks (waves independent)
    for (int gb = wid; gb < NGB32; gb += 4) {
        v8h b20, b21;
        if constexpr (USE_WS) {
            const v8h* b2p = (const v8h*)(B2buf + gb * 1024);
            b20 = b2p[lane];
            b21 = b2p[64 + lane];
        } else {
#pragma unroll
            for (int j = 0; j < 8; ++j) {
                const int gg = gb * 32 + ((j < 4) ? (lhi * 4 + j) : (16 + lhi * 4 + (j - 4)));
                const float qg = qw[gg];
                b20[j] = (f16)(Y[llo * G_TOT + gg] * qg);
                const int k1 = 16 + llo;
                b21[j] = (f16)((k1 < 25) ? Y[k1 * G_TOT + gg] * qg : 0.0f);
            }
        }

        v8h a2f[6];
#pragma unroll
        for (int gh = 0; gh < 2; ++gh) {
            v8h a1;
            if constexpr (USE_WS) {
                a1 = ((const v8h*)(A1buf + gb * 1024))[gh * 64 + lane];
            } else {
                const int g0 = gb * 32 + gh * 16 + llo;
#pragma unroll
                for (int j = 0; j < 8; ++j) {
                    const int k = (j < 4) ? (lhi * 4 + j) : (16 + lhi * 4 + (j - 4));
                    a1[j] = (f16)((k < 25) ? Y[k * G_TOT + g0] : 0.0f);
                }
            }

            // MFMA1: accg[s][Rn] lane,j = G^T[g = gb*32+gh*16+lhi*4+j][row = Rn*16+llo]
            v4f accg[2][6];
#pragma unroll
            for (int s = 0; s < 2; ++s)
#pragma unroll
                for (int Rn = 0; Rn < 6; ++Rn)
                    accg[s][Rn] = __builtin_amdgcn_mfma_f32_16x16x32_f16(
                        a1, hfrag[s][Rn], zero4, 0, 0, 0);

            // cross product -> A-fragment of MFMA2 (elem gh*4+j <-> k-half gh)
#pragma unroll
            for (int h = 0; h < 2; ++h)
#pragma unroll
                for (int j = 0; j < 4; ++j) {
                    const float g10 = accg[0][h][j], g11 = accg[0][2 + h][j], g12 = accg[0][4 + h][j];
                    const float g20 = accg[1][h][j], g21 = accg[1][2 + h][j], g22 = accg[1][4 + h][j];
                    const int e = gh * 4 + j;
                    a2f[h][e]     = (f16)(g11 * g22 - g12 * g21);
                    a2f[2 + h][e] = (f16)(g12 * g20 - g10 * g22);
                    a2f[4 + h][e] = (f16)(g10 * g21 - g11 * g20);
                }
        }

        // MFMA2: CO accumulation over 32 g in one instruction per (Rn,t)
#pragma unroll
        for (int Rn = 0; Rn < 6; ++Rn) {
            coacc[Rn][0] = __builtin_amdgcn_mfma_f32_16x16x32_f16(a2f[Rn], b20, coacc[Rn][0], 0, 0, 0);
            coacc[Rn][1] = __builtin_amdgcn_mfma_f32_16x16x32_f16(a2f[Rn], b21, coacc[Rn][1], 0, 0, 0);
        }
    }

    // ---- reduce 4 waves' partial CO into LDS (deterministic staged sum)
    __syncthreads();
    for (int w = 0; w < 4; ++w) {
        if (wid == w) {
#pragma unroll
            for (int Rn = 0; Rn < 6; ++Rn)
#pragma unroll
                for (int t = 0; t < 2; ++t)
#pragma unroll
                    for (int j = 0; j < 4; ++j) {
                        const int row = Rn * 16 + lhi * 4 + j;
                        const int col = t * 16 + llo;
                        if (w == 0) cob[row * CSTR + col] = coacc[Rn][t][j];
                        else        cob[row * CSTR + col] += coacc[Rn][t][j];
                    }
        }
        __syncthreads();
    }

    // ---- epilogue: out[n, p*32+b, v, k] = sum_a co[v*32+a][k] * Wout[p,l_k,a,b]
    const float* Wop = Wouts + p * 5120;
    float* outp = out + (n * 96 + p * 32) * 75;
    for (int idx = tid; idx < 300; idx += 256) {
        const int vk = idx % 75, q = idx / 75;
        const int v = vk / 25, k = vk - v * 25;
        const int l = (k >= 16) ? 4 : (k >= 9) ? 3 : (k >= 4) ? 2 : (k >= 1) ? 1 : 0;
        const float* w = Wop + l * 1024 + q * 8;
        float acc[8];
#pragma unroll
        for (int b = 0; b < 8; ++b) acc[b] = 0.0f;
        for (int a = 0; a < 32; ++a) {
            const float cv = cob[(v * 32 + a) * CSTR + k];
#pragma unroll
            for (int b = 0; b < 8; ++b) acc[b] += cv * w[a * 32 + b];
        }
#pragma unroll
        for (int b = 0; b < 8; ++b) outp[(q * 8 + b) * 75 + vk] = acc[b];
    }
}

extern "C" void kernel_launch(void* const* d_in, const int* in_sizes, int n_in,
                              void* d_out, int out_size, void* d_ws, size_t ws_size,
                              hipStream_t stream) {
    const float* x1 = (const float*)d_in[0];
    const float* x2 = (const float*)d_in[1];
    const float* W1s = (const float*)d_in[2];
    const float* W2s = (const float*)d_in[3];
    const float* Wouts = (const float*)d_in[4];
    const float* Y = (const float*)d_in[5];
    const float* qw = (const float*)d_in[6];
    float* out = (float*)d_out;

    f16* A1buf = (f16*)d_ws;
    f16* B2buf = (f16*)((char*)d_ws + 129024);

    if (ws_size >= 258048) {
        vg_prep<<<NGB32, 64, 0, stream>>>(Y, qw, A1buf, B2buf);
        vg_main<true><<<1536, 256, 0, stream>>>(x1, x2, W1s, W2s, Wouts, Y, qw,
                                                A1buf, B2buf, out);
    } else {
        vg_main<false><<<1536, 256, 0, stream>>>(x1, x2, W1s, W2s, Wouts, Y, qw,
                                                 nullptr, nullptr, out);
    }
}

// Round 3
// 115.526 us; speedup vs baseline: 3.8222x; 3.8222x over previous
//
#include <hip/hip_runtime.h>

#define G_TOT 2016
#define NGB32 63
#define HSTR 40   // hbuf row stride in f16 (80B): fragment-contiguous, 2-way banks
#define CSTR 33   // cob row stride (f32)

typedef _Float16 f16;
typedef __attribute__((ext_vector_type(4))) _Float16 v4h;
typedef __attribute__((ext_vector_type(8))) _Float16 v8h;
typedef __attribute__((ext_vector_type(4))) float v4f;

// slot(k) within a row: fragment elem order for lane group lhi = k>>2 (k<16)
// elems 0-3 <-> k = lhi*4+j, elems 4-7 <-> k = 16+lhi*4+j
__device__ __forceinline__ int kslot(int k) {
    return (k < 16) ? ((k >> 2) * 8 + (k & 3)) : (((k - 16) >> 2) * 8 + 4 + ((k - 16) & 3));
}

// ---------------------------------------------------------------------------
// Prep: gather Y into x32-MFMA-fragment-ordered f16 tables (per 32-g block).
// A1buf: A-operand of G^T gemm (m=g, k=ksh). B2buf: B-operand of CO gemm
// (k=g, n=ksh), qw folded in.
// ---------------------------------------------------------------------------
__global__ void vg_prep(const float* __restrict__ Y, const float* __restrict__ qw,
                        f16* __restrict__ A1buf, f16* __restrict__ B2buf) {
    const int gb = blockIdx.x;
    const int lane = threadIdx.x & 63;
    const int lhi = lane >> 4, llo = lane & 15;
#pragma unroll
    for (int gh = 0; gh < 2; ++gh) {
        const int g = gb * 32 + gh * 16 + llo;
#pragma unroll
        for (int j = 0; j < 8; ++j) {
            const int k = (j < 4) ? (lhi * 4 + j) : (16 + lhi * 4 + (j - 4));
            const float v = (k < 25) ? Y[k * G_TOT + g] : 0.0f;
            A1buf[((gb * 2 + gh) * 64 + lane) * 8 + j] = (f16)v;
        }
    }
#pragma unroll
    for (int t = 0; t < 2; ++t) {
        const int k = t * 16 + llo;
#pragma unroll
        for (int j = 0; j < 8; ++j) {
            const int g = gb * 32 + ((j < 4) ? (lhi * 4 + j) : (16 + lhi * 4 + (j - 4)));
            const float v = (k < 25) ? Y[k * G_TOT + g] * qw[g] : 0.0f;
            B2buf[((gb * 2 + t) * 64 + lane) * 8 + j] = (f16)v;
        }
    }
}

// ---------------------------------------------------------------------------
// Main fused kernel: one block per (n, parity), 4 waves, 32-g blocks.
// MFMA1 (swapped, x32): D1[g][row] = sum_ksh Y[ksh][g] * h[row][ksh]
// cross in-register (per c-half h to bound liveness) -> A-fragment of MFMA2
// MFMA2 (x32): CO[row][ksh] += sum_g cr[row][g] * Yw[ksh][g]
// ---------------------------------------------------------------------------
template <bool USE_WS>
__global__ __launch_bounds__(256, 2)
void vg_main(const float* __restrict__ x1, const float* __restrict__ x2,
             const float* __restrict__ W1s, const float* __restrict__ W2s,
             const float* __restrict__ Wouts, const float* __restrict__ Y,
             const float* __restrict__ qw,
             const f16* __restrict__ A1buf, const f16* __restrict__ B2buf,
             float* __restrict__ out) {
    __shared__ __align__(16) char smem[28032];
    f16* hb = (f16*)smem;                 // [2][96][HSTR] f16, fragment-contiguous
    float* cob = (float*)(smem + 15360);  // [96][CSTR] f32

    const int bid = blockIdx.x;
    const int n = bid / 3, p = bid % 3;
    const int tid = threadIdx.x;
    const int wid = tid >> 6;
    const int lane = tid & 63;
    const int lhi = lane >> 4, llo = lane & 15;

    // ---- phase 0a: zero hb (padding slots must be 0)
    for (int i = tid; i < 3840; i += 256) ((float*)smem)[i] = 0.0f;
    __syncthreads();

    // ---- phase 0b: h[row=v*32+c][k] = sum_f x[f,v,k] * W[l_k,f,c], cast f16.
    {
        const int c = tid & 31, grp = tid >> 5;
        const float* x1n = x1 + n * 2400;
        const float* x2n = x2 + n * 2400;
        const float* W1p = W1s + p * 5120;
        const float* W2p = W2s + p * 5120;
        for (int vk = grp; vk < 75; vk += 8) {
            const int v = vk / 25, k = vk - v * 25;
            const int l = (k >= 16) ? 4 : (k >= 9) ? 3 : (k >= 4) ? 2 : (k >= 1) ? 1 : 0;
            const float* w1 = W1p + l * 1024 + c;
            const float* w2 = W2p + l * 1024 + c;
            float a1 = 0.0f, a2s = 0.0f;
#pragma unroll
            for (int f = 0; f < 32; ++f) {
                a1 += x1n[f * 75 + vk] * w1[f * 32];
                a2s += x2n[f * 75 + vk] * w2[f * 32];
            }
            const int row = v * 32 + c;
            const int sl = kslot(k);
            hb[row * HSTR + sl] = (f16)a1;
            hb[96 * HSTR + row * HSTR + sl] = (f16)a2s;
        }
    }
    __syncthreads();

    // ---- h fragments (B-operand of MFMA1, x32): one b128 per fragment
    const f16* hfb = &hb[llo * HSTR + lhi * 8];
#define HFRAG(s, Rn) (*(const v8h*)(hfb + ((s) * 96 + (Rn) * 16) * HSTR))

    const v4f zero4 = {0.0f, 0.0f, 0.0f, 0.0f};
    v4f coacc[6][2];
#pragma unroll
    for (int Rn = 0; Rn < 6; ++Rn)
#pragma unroll
        for (int t = 0; t < 2; ++t) coacc[Rn][t] = zero4;

    // ---- main loop over 32-g blocks (waves independent)
    for (int gb = wid; gb < NGB32; gb += 4) {
        v8h b20, b21;
        if constexpr (USE_WS) {
            const v8h* b2p = (const v8h*)(B2buf + gb * 1024);
            b20 = b2p[lane];
            b21 = b2p[64 + lane];
        } else {
#pragma unroll
            for (int j = 0; j < 8; ++j) {
                const int gg = gb * 32 + ((j < 4) ? (lhi * 4 + j) : (16 + lhi * 4 + (j - 4)));
                const float qg = qw[gg];
                b20[j] = (f16)(Y[llo * G_TOT + gg] * qg);
                const int k1 = 16 + llo;
                b21[j] = (f16)((k1 < 25) ? Y[k1 * G_TOT + gg] * qg : 0.0f);
            }
        }

        v8h a2f[6];
#pragma unroll
        for (int gh = 0; gh < 2; ++gh) {
            v8h a1;
            if constexpr (USE_WS) {
                a1 = ((const v8h*)(A1buf + gb * 1024))[gh * 64 + lane];
            } else {
                const int g0 = gb * 32 + gh * 16 + llo;
#pragma unroll
                for (int j = 0; j < 8; ++j) {
                    const int k = (j < 4) ? (lhi * 4 + j) : (16 + lhi * 4 + (j - 4));
                    a1[j] = (f16)((k < 25) ? Y[k * G_TOT + g0] : 0.0f);
                }
            }

            // per c-half h: 6 MFMAs (24 transient VGPRs), then cross for this h
#pragma unroll
            for (int h = 0; h < 2; ++h) {
                v4f ag[2][3];
#pragma unroll
                for (int s = 0; s < 2; ++s)
#pragma unroll
                    for (int vc = 0; vc < 3; ++vc)
                        ag[s][vc] = __builtin_amdgcn_mfma_f32_16x16x32_f16(
                            a1, HFRAG(s, 2 * vc + h), zero4, 0, 0, 0);
#pragma unroll
                for (int j = 0; j < 4; ++j) {
                    const float g10 = ag[0][0][j], g11 = ag[0][1][j], g12 = ag[0][2][j];
                    const float g20 = ag[1][0][j], g21 = ag[1][1][j], g22 = ag[1][2][j];
                    const int e = gh * 4 + j;
                    a2f[h][e]     = (f16)(g11 * g22 - g12 * g21);
                    a2f[2 + h][e] = (f16)(g12 * g20 - g10 * g22);
                    a2f[4 + h][e] = (f16)(g10 * g21 - g11 * g20);
                }
            }
        }

        // MFMA2: CO accumulation over 32 g in one instruction per (Rn,t)
#pragma unroll
        for (int Rn = 0; Rn < 6; ++Rn) {
            coacc[Rn][0] = __builtin_amdgcn_mfma_f32_16x16x32_f16(a2f[Rn], b20, coacc[Rn][0], 0, 0, 0);
            coacc[Rn][1] = __builtin_amdgcn_mfma_f32_16x16x32_f16(a2f[Rn], b21, coacc[Rn][1], 0, 0, 0);
        }
    }
#undef HFRAG

    // ---- reduce 4 waves' partial CO into LDS (deterministic staged sum)
    __syncthreads();
    for (int w = 0; w < 4; ++w) {
        if (wid == w) {
#pragma unroll
            for (int Rn = 0; Rn < 6; ++Rn)
#pragma unroll
                for (int t = 0; t < 2; ++t)
#pragma unroll
                    for (int j = 0; j < 4; ++j) {
                        const int row = Rn * 16 + lhi * 4 + j;
                        const int col = t * 16 + llo;
                        if (w == 0) cob[row * CSTR + col] = coacc[Rn][t][j];
                        else        cob[row * CSTR + col] += coacc[Rn][t][j];
                    }
        }
        __syncthreads();
    }

    // ---- epilogue: out[n, p*32+b, v, k] = sum_a co[v*32+a][k] * Wout[p,l_k,a,b]
    const float* Wop = Wouts + p * 5120;
    float* outp = out + (n * 96 + p * 32) * 75;
    for (int idx = tid; idx < 300; idx += 256) {
        const int vk = idx % 75, q = idx / 75;
        const int v = vk / 25, k = vk - v * 25;
        const int l = (k >= 16) ? 4 : (k >= 9) ? 3 : (k >= 4) ? 2 : (k >= 1) ? 1 : 0;
        const float* w = Wop + l * 1024 + q * 8;
        float acc[8];
#pragma unroll
        for (int b = 0; b < 8; ++b) acc[b] = 0.0f;
        for (int a = 0; a < 32; ++a) {
            const float cv = cob[(v * 32 + a) * CSTR + k];
#pragma unroll
            for (int b = 0; b < 8; ++b) acc[b] += cv * w[a * 32 + b];
        }
#pragma unroll
        for (int b = 0; b < 8; ++b) outp[(q * 8 + b) * 75 + vk] = acc[b];
    }
}

extern "C" void kernel_launch(void* const* d_in, const int* in_sizes, int n_in,
                              void* d_out, int out_size, void* d_ws, size_t ws_size,
                              hipStream_t stream) {
    const float* x1 = (const float*)d_in[0];
    const float* x2 = (const float*)d_in[1];
    const float* W1s = (const float*)d_in[2];
    const float* W2s = (const float*)d_in[3];
    const float* Wouts = (const float*)d_in[4];
    const float* Y = (const float*)d_in[5];
    const float* qw = (const float*)d_in[6];
    float* out = (float*)d_out;

    f16* A1buf = (f16*)d_ws;
    f16* B2buf = (f16*)((char*)d_ws + 129024);

    if (ws_size >= 258048) {
        vg_prep<<<NGB32, 64, 0, stream>>>(Y, qw, A1buf, B2buf);
        vg_main<true><<<1536, 256, 0, stream>>>(x1, x2, W1s, W2s, Wouts, Y, qw,
                                                A1buf, B2buf, out);
    } else {
        vg_main<false><<<1536, 256, 0, stream>>>(x1, x2, W1s, W2s, Wouts, Y, qw,
                                                 nullptr, nullptr, out);
    }
}

// Round 4
// 112.302 us; speedup vs baseline: 3.9319x; 1.0287x over previous
//
#include <hip/hip_runtime.h>

#define G_TOT 2016
#define NGB32 63
#define HSTR 40   // hbuf row stride in f16 (80B): fragment-contiguous, 2-way banks
#define CSTR 33   // cob row stride (f32)

typedef _Float16 f16;
typedef __attribute__((ext_vector_type(4))) _Float16 v4h;
typedef __attribute__((ext_vector_type(8))) _Float16 v8h;
typedef __attribute__((ext_vector_type(4))) float v4f;

// slot(k) within a row: fragment elem order for lane group lhi = k>>2 (k<16)
// elems 0-3 <-> k = lhi*4+j, elems 4-7 <-> k = 16+lhi*4+j
__device__ __forceinline__ int kslot(int k) {
    return (k < 16) ? ((k >> 2) * 8 + (k & 3)) : (((k - 16) >> 2) * 8 + 4 + ((k - 16) & 3));
}

// ---------------------------------------------------------------------------
// Prep: gather Y into x32-MFMA-fragment-ordered f16 tables (per 32-g block).
// A1buf: A-operand of G^T gemm (m=g, k=ksh). B2buf: B-operand of CO gemm
// (k=g, n=ksh), qw folded in.
// ---------------------------------------------------------------------------
__global__ void vg_prep(const float* __restrict__ Y, const float* __restrict__ qw,
                        f16* __restrict__ A1buf, f16* __restrict__ B2buf) {
    const int gb = blockIdx.x;
    const int lane = threadIdx.x & 63;
    const int lhi = lane >> 4, llo = lane & 15;
#pragma unroll
    for (int gh = 0; gh < 2; ++gh) {
        const int g = gb * 32 + gh * 16 + llo;
#pragma unroll
        for (int j = 0; j < 8; ++j) {
            const int k = (j < 4) ? (lhi * 4 + j) : (16 + lhi * 4 + (j - 4));
            const float v = (k < 25) ? Y[k * G_TOT + g] : 0.0f;
            A1buf[((gb * 2 + gh) * 64 + lane) * 8 + j] = (f16)v;
        }
    }
#pragma unroll
    for (int t = 0; t < 2; ++t) {
        const int k = t * 16 + llo;
#pragma unroll
        for (int j = 0; j < 8; ++j) {
            const int g = gb * 32 + ((j < 4) ? (lhi * 4 + j) : (16 + lhi * 4 + (j - 4)));
            const float v = (k < 25) ? Y[k * G_TOT + g] * qw[g] : 0.0f;
            B2buf[((gb * 2 + t) * 64 + lane) * 8 + j] = (f16)v;
        }
    }
}

// ---------------------------------------------------------------------------
// Main fused kernel: one block per (n, parity), 4 waves, 32-g blocks.
// h-fragments hoisted to registers (48 VGPR) -> NO LDS reads in main loop.
// MFMA1 (swapped, x32): D1[g][row] = sum_ksh Y[ksh][g] * h[row][ksh]
// cross in-register -> A-fragment of MFMA2
// MFMA2 (x32): CO[row][ksh] += sum_g cr[row][g] * Yw[ksh][g]
// 1-deep register prefetch of next gb's a1/b2 (ws is L2-resident).
// ---------------------------------------------------------------------------
template <bool USE_WS>
__global__ __launch_bounds__(256, 2)
void vg_main(const float* __restrict__ x1, const float* __restrict__ x2,
             const float* __restrict__ W1s, const float* __restrict__ W2s,
             const float* __restrict__ Wouts, const float* __restrict__ Y,
             const float* __restrict__ qw,
             const f16* __restrict__ A1buf, const f16* __restrict__ B2buf,
             float* __restrict__ out) {
    __shared__ __align__(16) char smem[28032];
    f16* hb = (f16*)smem;                 // [2][96][HSTR] f16, fragment-contiguous
    float* cob = (float*)(smem + 15360);  // [96][CSTR] f32

    const int bid = blockIdx.x;
    const int n = bid / 3, p = bid % 3;
    const int tid = threadIdx.x;
    const int wid = tid >> 6;
    const int lane = tid & 63;
    const int lhi = lane >> 4, llo = lane & 15;

    // ---- phase 0a: zero hb (padding slots must be 0)
    for (int i = tid; i < 3840; i += 256) ((float*)smem)[i] = 0.0f;
    __syncthreads();

    // ---- phase 0b: h[row=v*32+c][k] = sum_f x[f,v,k] * W[l_k,f,c], cast f16.
    {
        const int c = tid & 31, grp = tid >> 5;
        const float* x1n = x1 + n * 2400;
        const float* x2n = x2 + n * 2400;
        const float* W1p = W1s + p * 5120;
        const float* W2p = W2s + p * 5120;
        for (int vk = grp; vk < 75; vk += 8) {
            const int v = vk / 25, k = vk - v * 25;
            const int l = (k >= 16) ? 4 : (k >= 9) ? 3 : (k >= 4) ? 2 : (k >= 1) ? 1 : 0;
            const float* w1 = W1p + l * 1024 + c;
            const float* w2 = W2p + l * 1024 + c;
            float a1 = 0.0f, a2s = 0.0f;
#pragma unroll
            for (int f = 0; f < 32; ++f) {
                a1 += x1n[f * 75 + vk] * w1[f * 32];
                a2s += x2n[f * 75 + vk] * w2[f * 32];
            }
            const int row = v * 32 + c;
            const int sl = kslot(k);
            hb[row * HSTR + sl] = (f16)a1;
            hb[96 * HSTR + row * HSTR + sl] = (f16)a2s;
        }
    }
    __syncthreads();

    // ---- hoist h fragments into registers: 12 x v8h = 48 VGPR, g-invariant
    v8h hfr[2][6];
    {
        const f16* hfb = &hb[llo * HSTR + lhi * 8];
#pragma unroll
        for (int s = 0; s < 2; ++s)
#pragma unroll
            for (int Rn = 0; Rn < 6; ++Rn)
                hfr[s][Rn] = *(const v8h*)(hfb + (s * 96 + Rn * 16) * HSTR);
    }

    const v4f zero4 = {0.0f, 0.0f, 0.0f, 0.0f};
    v4f coacc[6][2];
#pragma unroll
    for (int Rn = 0; Rn < 6; ++Rn)
#pragma unroll
        for (int t = 0; t < 2; ++t) coacc[Rn][t] = zero4;

    // ---- main loop over 32-g blocks (waves independent), reg-only inner body
    if constexpr (USE_WS) {
        const v8h* a1b = (const v8h*)A1buf;   // [gb][gh][lane] of v8h, 128 per gb
        const v8h* b2b = (const v8h*)B2buf;
        const int gb0 = wid;
        v8h a10 = a1b[gb0 * 128 + lane];
        v8h a11 = a1b[gb0 * 128 + 64 + lane];
        v8h b20 = b2b[gb0 * 128 + lane];
        v8h b21 = b2b[gb0 * 128 + 64 + lane];
        for (int gb = wid; gb < NGB32; gb += 4) {
            int gbn = gb + 4;
            if (gbn >= NGB32) gbn = gb;
            // prefetch next iteration (hides L2 latency under MFMAs below)
            v8h a10n = a1b[gbn * 128 + lane];
            v8h a11n = a1b[gbn * 128 + 64 + lane];
            v8h b20n = b2b[gbn * 128 + lane];
            v8h b21n = b2b[gbn * 128 + 64 + lane];

            v8h a2f[6];
#pragma unroll
            for (int gh = 0; gh < 2; ++gh) {
                const v8h a1 = gh ? a11 : a10;
#pragma unroll
                for (int h = 0; h < 2; ++h) {
                    v4f ag[2][3];
#pragma unroll
                    for (int s = 0; s < 2; ++s)
#pragma unroll
                        for (int vc = 0; vc < 3; ++vc)
                            ag[s][vc] = __builtin_amdgcn_mfma_f32_16x16x32_f16(
                                a1, hfr[s][2 * vc + h], zero4, 0, 0, 0);
#pragma unroll
                    for (int j = 0; j < 4; ++j) {
                        const float g10 = ag[0][0][j], g11 = ag[0][1][j], g12 = ag[0][2][j];
                        const float g20 = ag[1][0][j], g21 = ag[1][1][j], g22 = ag[1][2][j];
                        const int e = gh * 4 + j;
                        a2f[h][e]     = (f16)(g11 * g22 - g12 * g21);
                        a2f[2 + h][e] = (f16)(g12 * g20 - g10 * g22);
                        a2f[4 + h][e] = (f16)(g10 * g21 - g11 * g20);
                    }
                }
            }
#pragma unroll
            for (int Rn = 0; Rn < 6; ++Rn) {
                coacc[Rn][0] = __builtin_amdgcn_mfma_f32_16x16x32_f16(a2f[Rn], b20, coacc[Rn][0], 0, 0, 0);
                coacc[Rn][1] = __builtin_amdgcn_mfma_f32_16x16x32_f16(a2f[Rn], b21, coacc[Rn][1], 0, 0, 0);
            }
            a10 = a10n; a11 = a11n; b20 = b20n; b21 = b21n;
        }
    } else {
        for (int gb = wid; gb < NGB32; gb += 4) {
            v8h b20, b21;
#pragma unroll
            for (int j = 0; j < 8; ++j) {
                const int gg = gb * 32 + ((j < 4) ? (lhi * 4 + j) : (16 + lhi * 4 + (j - 4)));
                const float qg = qw[gg];
                b20[j] = (f16)(Y[llo * G_TOT + gg] * qg);
                const int k1 = 16 + llo;
                b21[j] = (f16)((k1 < 25) ? Y[k1 * G_TOT + gg] * qg : 0.0f);
            }
            v8h a2f[6];
#pragma unroll
            for (int gh = 0; gh < 2; ++gh) {
                v8h a1;
                const int g0 = gb * 32 + gh * 16 + llo;
#pragma unroll
                for (int j = 0; j < 8; ++j) {
                    const int k = (j < 4) ? (lhi * 4 + j) : (16 + lhi * 4 + (j - 4));
                    a1[j] = (f16)((k < 25) ? Y[k * G_TOT + g0] : 0.0f);
                }
#pragma unroll
                for (int h = 0; h < 2; ++h) {
                    v4f ag[2][3];
#pragma unroll
                    for (int s = 0; s < 2; ++s)
#pragma unroll
                        for (int vc = 0; vc < 3; ++vc)
                            ag[s][vc] = __builtin_amdgcn_mfma_f32_16x16x32_f16(
                                a1, hfr[s][2 * vc + h], zero4, 0, 0, 0);
#pragma unroll
                    for (int j = 0; j < 4; ++j) {
                        const float g10 = ag[0][0][j], g11 = ag[0][1][j], g12 = ag[0][2][j];
                        const float g20 = ag[1][0][j], g21 = ag[1][1][j], g22 = ag[1][2][j];
                        const int e = gh * 4 + j;
                        a2f[h][e]     = (f16)(g11 * g22 - g12 * g21);
                        a2f[2 + h][e] = (f16)(g12 * g20 - g10 * g22);
                        a2f[4 + h][e] = (f16)(g10 * g21 - g11 * g20);
                    }
                }
            }
#pragma unroll
            for (int Rn = 0; Rn < 6; ++Rn) {
                coacc[Rn][0] = __builtin_amdgcn_mfma_f32_16x16x32_f16(a2f[Rn], b20, coacc[Rn][0], 0, 0, 0);
                coacc[Rn][1] = __builtin_amdgcn_mfma_f32_16x16x32_f16(a2f[Rn], b21, coacc[Rn][1], 0, 0, 0);
            }
        }
    }

    // ---- reduce 4 waves' partial CO into LDS (deterministic staged sum)
    __syncthreads();
    for (int w = 0; w < 4; ++w) {
        if (wid == w) {
#pragma unroll
            for (int Rn = 0; Rn < 6; ++Rn)
#pragma unroll
                for (int t = 0; t < 2; ++t)
#pragma unroll
                    for (int j = 0; j < 4; ++j) {
                        const int row = Rn * 16 + lhi * 4 + j;
                        const int col = t * 16 + llo;
                        if (w == 0) cob[row * CSTR + col] = coacc[Rn][t][j];
                        else        cob[row * CSTR + col] += coacc[Rn][t][j];
                    }
        }
        __syncthreads();
    }

    // ---- epilogue: out[n, p*32+b, v, k] = sum_a co[v*32+a][k] * Wout[p,l_k,a,b]
    const float* Wop = Wouts + p * 5120;
    float* outp = out + (n * 96 + p * 32) * 75;
    for (int idx = tid; idx < 300; idx += 256) {
        const int vk = idx % 75, q = idx / 75;
        const int v = vk / 25, k = vk - v * 25;
        const int l = (k >= 16) ? 4 : (k >= 9) ? 3 : (k >= 4) ? 2 : (k >= 1) ? 1 : 0;
        const float* w = Wop + l * 1024 + q * 8;
        float acc[8];
#pragma unroll
        for (int b = 0; b < 8; ++b) acc[b] = 0.0f;
        for (int a = 0; a < 32; ++a) {
            const float cv = cob[(v * 32 + a) * CSTR + k];
#pragma unroll
            for (int b = 0; b < 8; ++b) acc[b] += cv * w[a * 32 + b];
        }
#pragma unroll
        for (int b = 0; b < 8; ++b) outp[(q * 8 + b) * 75 + vk] = acc[b];
    }
}

extern "C" void kernel_launch(void* const* d_in, const int* in_sizes, int n_in,
                              void* d_out, int out_size, void* d_ws, size_t ws_size,
                              hipStream_t stream) {
    const float* x1 = (const float*)d_in[0];
    const float* x2 = (const float*)d_in[1];
    const float* W1s = (const float*)d_in[2];
    const float* W2s = (const float*)d_in[3];
    const float* Wouts = (const float*)d_in[4];
    const float* Y = (const float*)d_in[5];
    const float* qw = (const float*)d_in[6];
    float* out = (float*)d_out;

    f16* A1buf = (f16*)d_ws;
    f16* B2buf = (f16*)((char*)d_ws + 129024);

    if (ws_size >= 258048) {
        vg_prep<<<NGB32, 64, 0, stream>>>(Y, qw, A1buf, B2buf);
        vg_main<true><<<1536, 256, 0, stream>>>(x1, x2, W1s, W2s, Wouts, Y, qw,
                                                A1buf, B2buf, out);
    } else {
        vg_main<false><<<1536, 256, 0, stream>>>(x1, x2, W1s, W2s, Wouts, Y, qw,
                                                 nullptr, nullptr, out);
    }
}